// Round 1
// baseline (955.483 us; speedup 1.0000x reference)
//
#include <hip/hip_runtime.h>
#include <math.h>
#include <stdint.h>

// ChunkedSelfAttention: B=4, L=4096, H=16, DH=DV=128, CHUNK=1024, causal in-chunk.
// Strategy: bf16 MFMA flash attention per chunk.
//   pre-pass 0: sincos table (4096 x 64 x {cos,sin} f32) -- 262K sincosf instead of 16.7M
//   pre-pass 1: rope(q)*scale*log2e, rope(k) -> bf16 ws, layout (b,n,h,ck,dh), 4-wide vectorized
//   pre-pass 2: v -> bf16 V^T ws, layout (b,n,h,dv,ck)
//   attention:  S^T = K.Q^T (32x32x16), softmax in-register (exp2 domain),
//               O^T += V^T.P^T (32x32x8 _1k); K/V next-tile register prefetch overlaps compute;
//               heavy q-tiles dispatched first; alpha-rescale skipped when running max unchanged.

typedef __attribute__((ext_vector_type(8)))  short bf16x8;
typedef __attribute__((ext_vector_type(4)))  short bf16x4;
typedef __attribute__((ext_vector_type(16))) float f32x16;
typedef __attribute__((ext_vector_type(4)))  float f32x4;
typedef __attribute__((ext_vector_type(4)))  unsigned short us4;

__device__ __forceinline__ unsigned short f2bf(float x) {  // RNE fp32->bf16
  unsigned u = __float_as_uint(x);
  u += 0x7fff + ((u >> 16) & 1);
  return (unsigned short)(u >> 16);
}

// pack two fp32 -> (bf16(lo) in low short, bf16(hi) in high short), RNE
__device__ __forceinline__ unsigned pk2(float lo, float hi) {
  unsigned u0 = __float_as_uint(lo); u0 += 0x7fff + ((u0 >> 16) & 1);
  unsigned u1 = __float_as_uint(hi); u1 += 0x7fff + ((u1 >> 16) & 1);
  return __builtin_amdgcn_perm(u1, u0, 0x07060302u);
}

// ---------------- sincos table: tab[l][d] = {cos,sin}(l * 10000^(-d/64)) ----------------
__global__ __launch_bounds__(256) void rope_tab_kernel(float* __restrict__ tab) {
  const int idx = blockIdx.x * 256 + threadIdx.x;  // 4096*64 entries
  const int l = idx >> 6, d = idx & 63;
  const float freq  = __builtin_amdgcn_exp2f((float)d * -0.20762050593046014f);
  const float angle = (float)l * freq;
  float sn, cs;
  sincosf(angle, &sn, &cs);
  *(float2*)(tab + (size_t)idx * 2) = make_float2(cs, sn);
}

// ---------------- RoPE + scale + bf16 cast for Q and K ----------------
// 16 lanes per (b,l,h) row; lane j handles dh {4j..4j+3, 64+4j..64+4j+3}
// block = 16 rows sharing one l -> table row (512B) is L1-resident
__global__ __launch_bounds__(256) void rope_kernel(
    const float* __restrict__ q, const float* __restrict__ k,
    const float* __restrict__ tab,
    unsigned short* __restrict__ qws, unsigned short* __restrict__ kws)
{
  const int t  = threadIdx.x;
  const int r  = blockIdx.x * 16 + (t >> 4);  // row over (b,l,h); total 262144
  const int j4 = (t & 15) * 4;
  const int b   = r >> 16;
  const int rem = r & 65535;
  const int l   = rem >> 4;
  const int h   = rem & 15;

  const f32x4* tb = (const f32x4*)(tab + (size_t)l * 128 + (size_t)j4 * 2);
  const f32x4 t0 = tb[0], t1 = tb[1];
  const f32x4 cs = { t0[0], t0[2], t1[0], t1[2] };
  const f32x4 sn = { t0[1], t0[3], t1[1], t1[3] };

  const size_t src = (size_t)r * 128 + j4;
  const int n = l >> 10, ck = l & 1023;
  const size_t dst = ((((size_t)b * 4 + n) * 16 + h) * 1024 + ck) * 128 + j4;
  const float QS = 0.12751741f;  // (1/sqrt(128)) * log2(e): S^T lands in exp2 domain

  {  // Q (scaled)
    f32x4 x1 = *(const f32x4*)(q + src);
    f32x4 x2 = *(const f32x4*)(q + src + 64);
    f32x4 y1, y2;
#pragma unroll
    for (int i = 0; i < 4; ++i) {
      y1[i] = (x1[i] * cs[i] - x2[i] * sn[i]) * QS;
      y2[i] = (x2[i] * cs[i] + x1[i] * sn[i]) * QS;
    }
    *(uint2*)(qws + dst)      = make_uint2(pk2(y1[0], y1[1]), pk2(y1[2], y1[3]));
    *(uint2*)(qws + dst + 64) = make_uint2(pk2(y2[0], y2[1]), pk2(y2[2], y2[3]));
  }
  {  // K (unscaled)
    f32x4 x1 = *(const f32x4*)(k + src);
    f32x4 x2 = *(const f32x4*)(k + src + 64);
    f32x4 y1, y2;
#pragma unroll
    for (int i = 0; i < 4; ++i) {
      y1[i] = x1[i] * cs[i] - x2[i] * sn[i];
      y2[i] = x2[i] * cs[i] + x1[i] * sn[i];
    }
    *(uint2*)(kws + dst)      = make_uint2(pk2(y1[0], y1[1]), pk2(y1[2], y1[3]));
    *(uint2*)(kws + dst + 64) = make_uint2(pk2(y2[0], y2[1]), pk2(y2[2], y2[3]));
  }
}

// ---------------- V -> bf16 V^T, layout (b,n,h,dv,ck) ----------------
// block per (b,n,h, 64-row l-slab); LDS-tiled transpose
__global__ __launch_bounds__(256) void vtrans_kernel(
    const float* __restrict__ v, unsigned short* __restrict__ vtws)
{
  __shared__ unsigned short tile[128 * 72];  // [dv][ck], stride 72 (144 B, 16B-mult)
  const int t   = threadIdx.x;
  const int ckb = blockIdx.x & 15;
  const int h   = (blockIdx.x >> 4) & 15;
  const int n   = (blockIdx.x >> 8) & 3;
  const int b   = blockIdx.x >> 10;
  const int i0  = (t >> 4) * 4;      // l within slab: 4 rows
  const int dv0 = (t & 15) * 8;      // 8 dv
  const int l0  = n * 1024 + ckb * 64;
  const float* src = v + (((size_t)b * 4096 + l0) * 16 + h) * 128;
  unsigned short vals[4][8];
#pragma unroll
  for (int i = 0; i < 4; ++i) {
    const float* p = src + (size_t)(i0 + i) * 2048 + dv0;  // l stride = H*DV
    f32x4 a = *(const f32x4*)p;
    f32x4 c = *(const f32x4*)(p + 4);
#pragma unroll
    for (int jj = 0; jj < 4; ++jj) { vals[i][jj] = f2bf(a[jj]); vals[i][4 + jj] = f2bf(c[jj]); }
  }
#pragma unroll
  for (int dd = 0; dd < 8; ++dd) {
    us4 pk = { vals[0][dd], vals[1][dd], vals[2][dd], vals[3][dd] };
    *(us4*)&tile[(dv0 + dd) * 72 + i0] = pk;  // ds_write_b64, 8B aligned
  }
  __syncthreads();
  const int dv = t >> 1, hf = t & 1;
  const size_t dstb = ((((size_t)b * 4 + n) * 16 + h) * 128 + dv) * 1024 + ckb * 64 + hf * 32;
  const unsigned short* sl = &tile[dv * 72 + hf * 32];
#pragma unroll
  for (int kk = 0; kk < 4; ++kk)
    *(uint4*)(vtws + dstb + kk * 8) = *(const uint4*)(sl + kk * 8);
}

// ---------------- flash attention over one chunk ----------------
// grid (qt=8, n*h=64, b=4); block 256 = 4 waves; wave owns 32 q-rows.
__global__ __launch_bounds__(256) void attn_kernel(
    const unsigned short* __restrict__ qws, const unsigned short* __restrict__ kws,
    const unsigned short* __restrict__ vtws, float* __restrict__ out)
{
  __shared__ unsigned short smem[64 * 136 + 128 * 72];  // 35840 B
  unsigned short* kt = smem;             // K tile [64 kv][136] (128 dh + 8 pad)
  unsigned short* vt = smem + 64 * 136;  // V^T tile [128 dv][72] (64 ck + 8 pad)
  unsigned short* qstage = smem;         // Q tile [128][136], prologue only (fits)

  const int qt   = 7 - (int)blockIdx.x;  // heavy blocks (big jmax) dispatch first
  const int nh   = blockIdx.y;
  const int b    = blockIdx.z;
  const int t    = threadIdx.x;
  const int lane = t & 63;
  const int w    = t >> 6;
  const int c    = lane & 31;   // q index for S^T/O^T frags
  const int g    = lane >> 5;

  const size_t bnh = (size_t)b * 64 + nh;
  const unsigned short* qbase = qws + bnh * (1024 * 128) + (size_t)qt * (128 * 128);
  const unsigned short* kbase = kws + bnh * (1024 * 128);
  const unsigned short* vbase = vtws + bnh * (128 * 1024);

  const int jmax = 2 * qt + 2;
  uint4 kreg[4], vreg[4];  // next-tile staging registers (T14 async split)

  // ---- stage Q tile (32 KB contiguous) into LDS, pull B-frags, then free LDS.
  // Q loads issue first (their ds_writes only wait on them); j=0 K/V prefetch
  // issues behind and completes during the qf pulls + barriers.
#pragma unroll
  for (int it = 0; it < 8; ++it) {
    int u = it * 256 + t;
    int row = u >> 4, col = u & 15;
    uint4 val = ((const uint4*)qbase)[u];
    *(uint4*)((char*)qstage + row * 272 + col * 16) = val;
  }
  {
    const uint4* kg = (const uint4*)kbase;
#pragma unroll
    for (int it = 0; it < 4; ++it) kreg[it] = kg[it * 256 + t];
#pragma unroll
    for (int it = 0; it < 4; ++it) {
      int u = it * 256 + t; int dv = u >> 3, col = u & 7;
      vreg[it] = *(const uint4*)(vbase + (size_t)dv * 1024 + col * 8);
    }
  }
  __syncthreads();
  const int qsub = w * 32;
  bf16x8 qf[8];  // B-frag f: q = qsub+c, dh = 16f + 8g + j
  {
    const char* qp = (const char*)qstage + (qsub + c) * 272 + g * 16;
#pragma unroll
    for (int f = 0; f < 8; ++f) qf[f] = *(const bf16x8*)(qp + f * 32);
  }
  __syncthreads();
  // ---- write j=0 K/V into LDS (overwrites qstage region)
#pragma unroll
  for (int it = 0; it < 4; ++it) {
    int u = it * 256 + t; int row = u >> 4, col = u & 15;
    *(uint4*)((char*)kt + row * 272 + col * 16) = kreg[it];
  }
#pragma unroll
  for (int it = 0; it < 4; ++it) {
    int u = it * 256 + t; int dv = u >> 3, col = u & 7;
    *(uint4*)((char*)vt + dv * 144 + col * 16) = vreg[it];
  }
  __syncthreads();

  f32x16 acc[4] = {};            // O^T: acc[d] = dv [32d,32d+32) x q; col=c=q
  float m_run = -INFINITY, l_run = 0.0f;
  const int q0w  = qt * 128 + qsub;
  const int rowq = q0w + c;      // this lane's q row (chunk-local)

  for (int j = 0; j < jmax; ++j) {
    const bool more = (j + 1) < jmax;
    // ---- issue next-tile global loads NOW; they fly under this tile's compute
    if (more) {
      const uint4* kg = (const uint4*)(kbase + (size_t)(j + 1) * (64 * 128));
#pragma unroll
      for (int it = 0; it < 4; ++it) kreg[it] = kg[it * 256 + t];
#pragma unroll
      for (int it = 0; it < 4; ++it) {
        int u = it * 256 + t; int dv = u >> 3, col = u & 7;
        vreg[it] = *(const uint4*)(vbase + (size_t)dv * 1024 + (j + 1) * 64 + col * 8);
      }
    }

    const int kv0 = j * 64;
    if (kv0 <= q0w + 31) {  // not fully masked for this wave
      // ---- S^T = K . Q^T : two 32(kv) x 32(q) tiles
      f32x16 s[2];
#pragma unroll
      for (int ks = 0; ks < 2; ++ks) {
        f32x16 a = {};
        const char* kp = (const char*)kt + (ks * 32 + c) * 272 + g * 16;
#pragma unroll
        for (int f = 0; f < 8; ++f) {
          bf16x8 kf = *(const bf16x8*)(kp + f * 32);  // A: kv=ks*32+c, dh=16f+8g+j
          a = __builtin_amdgcn_mfma_f32_32x32x16_bf16(kf, qf[f], a, 0, 0, 0);
        }
        s[ks] = a;
      }
      // ---- online softmax (exp2 domain; scale*log2e folded into Q)
      const bool needmask = (kv0 + 63) > q0w;
      float m0 = -3.0e38f, m1 = m0, m2 = m0, m3 = m0;  // 4-way tree max (short dep chains)
      if (needmask) {
#pragma unroll
        for (int ks = 0; ks < 2; ++ks)
#pragma unroll
          for (int r = 0; r < 16; r += 4) {
            const int base = kv0 + ks * 32 + 8 * (r >> 2) + 4 * g;
            float v0 = (base + 0 > rowq) ? -3.0e38f : s[ks][r + 0];
            float v1 = (base + 1 > rowq) ? -3.0e38f : s[ks][r + 1];
            float v2 = (base + 2 > rowq) ? -3.0e38f : s[ks][r + 2];
            float v3 = (base + 3 > rowq) ? -3.0e38f : s[ks][r + 3];
            s[ks][r + 0] = v0; s[ks][r + 1] = v1; s[ks][r + 2] = v2; s[ks][r + 3] = v3;
            m0 = fmaxf(m0, v0); m1 = fmaxf(m1, v1); m2 = fmaxf(m2, v2); m3 = fmaxf(m3, v3);
          }
      } else {
#pragma unroll
        for (int ks = 0; ks < 2; ++ks)
#pragma unroll
          for (int r = 0; r < 16; r += 4) {
            m0 = fmaxf(m0, s[ks][r + 0]); m1 = fmaxf(m1, s[ks][r + 1]);
            m2 = fmaxf(m2, s[ks][r + 2]); m3 = fmaxf(m3, s[ks][r + 3]);
          }
      }
      float mloc = fmaxf(fmaxf(m0, m1), fmaxf(m2, m3));
      mloc = fmaxf(mloc, __shfl_xor(mloc, 32));  // both g-halves hold q=c
      if (__any(mloc > m_run)) {   // skip rescale when running max unchanged (alpha==1)
        const float mnew  = fmaxf(m_run, mloc);
        const float alpha = __builtin_amdgcn_exp2f(m_run - mnew);
        l_run *= alpha;
#pragma unroll
        for (int d = 0; d < 4; ++d)
#pragma unroll
          for (int r = 0; r < 16; ++r) acc[d][r] *= alpha;
        m_run = mnew;
      }
      float r0 = 0.0f, r1 = 0.0f, r2 = 0.0f, r3 = 0.0f;
#pragma unroll
      for (int ks = 0; ks < 2; ++ks)
#pragma unroll
        for (int r = 0; r < 16; r += 4) {
          float p0 = __builtin_amdgcn_exp2f(s[ks][r + 0] - m_run); s[ks][r + 0] = p0; r0 += p0;
          float p1 = __builtin_amdgcn_exp2f(s[ks][r + 1] - m_run); s[ks][r + 1] = p1; r1 += p1;
          float p2 = __builtin_amdgcn_exp2f(s[ks][r + 2] - m_run); s[ks][r + 2] = p2; r2 += p2;
          float p3 = __builtin_amdgcn_exp2f(s[ks][r + 3] - m_run); s[ks][r + 3] = p3; r3 += p3;
        }
      float rsum = (r0 + r1) + (r2 + r3);
      rsum += __shfl_xor(rsum, 32);
      l_run += rsum;
      // ---- pack P^T frags: S^T D-regs 4o..4o+3 ARE the 32x32x8 B-frag (k=4g+j)
      bf16x4 pfr[8];
#pragma unroll
      for (int o = 0; o < 8; ++o) {
        const int ks = o >> 2, rb = 4 * (o & 3);
        union { unsigned uu[2]; bf16x4 bv; } pk;
        pk.uu[0] = pk2(s[ks][rb + 0], s[ks][rb + 1]);
        pk.uu[1] = pk2(s[ks][rb + 2], s[ks][rb + 3]);
        pfr[o] = pk.bv;
      }
      // ---- O^T += V^T . P^T   (A: dv=32d+c, kv=8o+4g+j from LDS b64)
      const char* vp = (const char*)vt + c * 144 + g * 8;
#pragma unroll
      for (int d = 0; d < 4; ++d) {
        f32x16 a = acc[d];
        const char* vpd = vp + d * 32 * 144;
#pragma unroll
        for (int o = 0; o < 8; ++o) {
          bf16x4 vf = *(const bf16x4*)(vpd + o * 16);
          a = __builtin_amdgcn_mfma_f32_32x32x8bf16_1k(vf, pfr[o], a, 0, 0, 0);
        }
        acc[d] = a;
      }
    }
    __syncthreads();           // all waves done reading LDS tile j
    if (more) {
      // ---- drain prefetch (vmcnt) and publish tile j+1
#pragma unroll
      for (int it = 0; it < 4; ++it) {
        int u = it * 256 + t; int row = u >> 4, col = u & 15;
        *(uint4*)((char*)kt + row * 272 + col * 16) = kreg[it];
      }
#pragma unroll
      for (int it = 0; it < 4; ++it) {
        int u = it * 256 + t; int dv = u >> 3, col = u & 7;
        *(uint4*)((char*)vt + dv * 144 + col * 16) = vreg[it];
      }
      __syncthreads();
    }
  }

  // ---- epilogue: O = O^T/l ; lane holds q=rowq, dv = 32d + 8e + 4g + rr
  const float invl = 1.0f / l_run;
  const int n = nh >> 4, h = nh & 15;
  const size_t orow = (((size_t)b * 4096 + n * 1024 + rowq) * 16 + h) * 128;
#pragma unroll
  for (int d = 0; d < 4; ++d)
#pragma unroll
    for (int e = 0; e < 4; ++e) {
      f32x4 vv;
#pragma unroll
      for (int rr = 0; rr < 4; ++rr) vv[rr] = acc[d][4 * e + rr] * invl;
      *(f32x4*)(out + orow + 32 * d + 8 * e + 4 * g) = vv;
    }
}

extern "C" void kernel_launch(void* const* d_in, const int* in_sizes, int n_in,
                              void* d_out, int out_size, void* d_ws, size_t ws_size,
                              hipStream_t stream) {
  const float* q = (const float*)d_in[0];
  const float* k = (const float*)d_in[1];
  const float* v = (const float*)d_in[2];
  float* out = (float*)d_out;
  // ws: qws | kws | vtws, each 4*4096*16*128 bf16 = 64 MB (192 MB total)
  unsigned short* qws  = (unsigned short*)d_ws;
  unsigned short* kws  = qws + (size_t)33554432;
  unsigned short* vtws = kws + (size_t)33554432;

  // sincos table (2 MB) overlays the vtws region: consumed by rope_kernel,
  // then fully overwritten by vtrans_kernel before attn reads vtws.
  float* tab = (float*)vtws;
  rope_tab_kernel<<<1024, 256, 0, stream>>>(tab);
  rope_kernel<<<16384, 256, 0, stream>>>(q, k, tab, qws, kws);
  vtrans_kernel<<<4096, 256, 0, stream>>>(v, vtws);
  attn_kernel<<<dim3(8, 64, 4), 256, 0, stream>>>(qws, kws, vtws, out);
}

// Round 2
// 725.048 us; speedup vs baseline: 1.3178x; 1.3178x over previous
//
#include <hip/hip_runtime.h>
#include <math.h>
#include <stdint.h>

// ChunkedSelfAttention: B=4, L=4096, H=16, DH=DV=128, CHUNK=1024, causal in-chunk.
// Strategy: bf16 MFMA flash attention per chunk.
//   pre-pass 0: sincos table (4096 x 64 x {cos,sin} f32)
//   pre-pass 1: rope(q)*scale*log2e -> qws (linear); rope(k) -> kws (XOR-swizzled rows)
//   pre-pass 2: v -> bf16 V^T ws (XOR-swizzled rows), layout (b,n,h,dv,ck)
//   attention:  K/V staged via global_load_lds (direct-to-LDS, 0 VGPR cost) into a
//               double-buffered LINEAR LDS tile; next tile's loads issued before compute
//               (2-phase async pipeline); swizzle gives conflict-free ds_reads.
//               S^T = K.Q^T (32x32x16), softmax in-register (exp2 domain),
//               O^T += V^T.P^T (32x32x8 _1k); heavy q-tiles dispatched first.

typedef __attribute__((ext_vector_type(8)))  short bf16x8;
typedef __attribute__((ext_vector_type(4)))  short bf16x4;
typedef __attribute__((ext_vector_type(16))) float f32x16;
typedef __attribute__((ext_vector_type(4)))  float f32x4;
typedef __attribute__((ext_vector_type(4)))  unsigned short us4;

__device__ __forceinline__ unsigned short f2bf(float x) {  // RNE fp32->bf16
  unsigned u = __float_as_uint(x);
  u += 0x7fff + ((u >> 16) & 1);
  return (unsigned short)(u >> 16);
}

// pack two fp32 -> (bf16(lo) low short, bf16(hi) high short), RNE
__device__ __forceinline__ unsigned pk2(float lo, float hi) {
  unsigned u0 = __float_as_uint(lo); u0 += 0x7fff + ((u0 >> 16) & 1);
  unsigned u1 = __float_as_uint(hi); u1 += 0x7fff + ((u1 >> 16) & 1);
  return __builtin_amdgcn_perm(u1, u0, 0x07060302u);
}

// async global->LDS, 16 B per lane; LDS dest = wave-uniform base + lane*16
__device__ __forceinline__ void glds16(const void* g, void* l) {
  __builtin_amdgcn_global_load_lds(
      (const __attribute__((address_space(1))) unsigned int*)g,
      (__attribute__((address_space(3))) unsigned int*)l, 16, 0, 0);
}

// ---------------- sincos table: tab[l][d] = {cos,sin}(l * 10000^(-d/64)) ----------------
__global__ __launch_bounds__(256) void rope_tab_kernel(float* __restrict__ tab) {
  const int idx = blockIdx.x * 256 + threadIdx.x;  // 4096*64 entries
  const int l = idx >> 6, d = idx & 63;
  const float freq  = __builtin_amdgcn_exp2f((float)d * -0.20762050593046014f);
  const float angle = (float)l * freq;
  float sn, cs;
  sincosf(angle, &sn, &cs);
  *(float2*)(tab + (size_t)idx * 2) = make_float2(cs, sn);
}

// ---------------- RoPE + scale + bf16 cast for Q and K ----------------
// 16 lanes per (b,l,h) row; lane j handles dh {4j..4j+3, 64+4j..64+4j+3}
// Q stored linear; K stored with per-row XOR swizzle (element col ^= (ck&15)<<3)
__global__ __launch_bounds__(256) void rope_kernel(
    const float* __restrict__ q, const float* __restrict__ k,
    const float* __restrict__ tab,
    unsigned short* __restrict__ qws, unsigned short* __restrict__ kws)
{
  const int t  = threadIdx.x;
  const int r  = blockIdx.x * 16 + (t >> 4);  // row over (b,l,h); total 262144
  const int j4 = (t & 15) * 4;
  const int b   = r >> 16;
  const int rem = r & 65535;
  const int l   = rem >> 4;
  const int h   = rem & 15;

  const f32x4* tb = (const f32x4*)(tab + (size_t)l * 128 + (size_t)j4 * 2);
  const f32x4 t0 = tb[0], t1 = tb[1];
  const f32x4 cs = { t0[0], t0[2], t1[0], t1[2] };
  const f32x4 sn = { t0[1], t0[3], t1[1], t1[3] };

  const size_t src = (size_t)r * 128 + j4;
  const int n = l >> 10, ck = l & 1023;
  const size_t dstrow = ((((size_t)b * 4 + n) * 16 + h) * 1024 + ck) * 128;
  const int swk = (ck & 15) << 3;  // element-domain row swizzle for K
  const float QS = 0.12751741f;    // (1/sqrt(128)) * log2(e)

  {  // Q (scaled, linear layout)
    f32x4 x1 = *(const f32x4*)(q + src);
    f32x4 x2 = *(const f32x4*)(q + src + 64);
    f32x4 y1, y2;
#pragma unroll
    for (int i = 0; i < 4; ++i) {
      y1[i] = (x1[i] * cs[i] - x2[i] * sn[i]) * QS;
      y2[i] = (x2[i] * cs[i] + x1[i] * sn[i]) * QS;
    }
    *(uint2*)(qws + dstrow + j4)      = make_uint2(pk2(y1[0], y1[1]), pk2(y1[2], y1[3]));
    *(uint2*)(qws + dstrow + j4 + 64) = make_uint2(pk2(y2[0], y2[1]), pk2(y2[2], y2[3]));
  }
  {  // K (unscaled, swizzled layout: element e holds logical dh = e ^ swk)
    f32x4 x1 = *(const f32x4*)(k + src);
    f32x4 x2 = *(const f32x4*)(k + src + 64);
    f32x4 y1, y2;
#pragma unroll
    for (int i = 0; i < 4; ++i) {
      y1[i] = x1[i] * cs[i] - x2[i] * sn[i];
      y2[i] = x2[i] * cs[i] + x1[i] * sn[i];
    }
    *(uint2*)(kws + dstrow + (j4 ^ swk))        = make_uint2(pk2(y1[0], y1[1]), pk2(y1[2], y1[3]));
    *(uint2*)(kws + dstrow + ((j4 + 64) ^ swk)) = make_uint2(pk2(y2[0], y2[1]), pk2(y2[2], y2[3]));
  }
}

// ---------------- V -> bf16 V^T, layout (b,n,h,dv,ck), swizzled rows ----------------
// block per (b,n,h, 64-row l-slab); LDS-tiled transpose; store col ^= (dv&15)<<2 (elements)
__global__ __launch_bounds__(256) void vtrans_kernel(
    const float* __restrict__ v, unsigned short* __restrict__ vtws)
{
  __shared__ unsigned short tile[128 * 72];  // [dv][ck], stride 72
  const int t   = threadIdx.x;
  const int ckb = blockIdx.x & 15;
  const int h   = (blockIdx.x >> 4) & 15;
  const int n   = (blockIdx.x >> 8) & 3;
  const int b   = blockIdx.x >> 10;
  const int i0  = (t >> 4) * 4;      // l within slab: 4 rows
  const int dv0 = (t & 15) * 8;      // 8 dv
  const int l0  = n * 1024 + ckb * 64;
  const float* src = v + (((size_t)b * 4096 + l0) * 16 + h) * 128;
  unsigned short vals[4][8];
#pragma unroll
  for (int i = 0; i < 4; ++i) {
    const float* p = src + (size_t)(i0 + i) * 2048 + dv0;  // l stride = H*DV
    f32x4 a = *(const f32x4*)p;
    f32x4 c = *(const f32x4*)(p + 4);
#pragma unroll
    for (int jj = 0; jj < 4; ++jj) { vals[i][jj] = f2bf(a[jj]); vals[i][4 + jj] = f2bf(c[jj]); }
  }
#pragma unroll
  for (int dd = 0; dd < 8; ++dd) {
    us4 pk = { vals[0][dd], vals[1][dd], vals[2][dd], vals[3][dd] };
    *(us4*)&tile[(dv0 + dd) * 72 + i0] = pk;  // ds_write_b64
  }
  __syncthreads();
  const int dv = t >> 1, hf = t & 1;
  const int swv = (dv & 15) << 2;  // element-domain row swizzle
  const size_t rowb = ((((size_t)b * 4 + n) * 16 + h) * 128 + dv) * 1024 + ckb * 64;
  const unsigned short* sl = &tile[dv * 72 + hf * 32];
#pragma unroll
  for (int kk = 0; kk < 4; ++kk) {
    uint4 w16 = *(const uint4*)(sl + kk * 8);   // elements c0..c0+7
    const int c0 = hf * 32 + kk * 8;
    *(uint2*)(vtws + rowb + (c0 ^ swv))       = make_uint2(w16.x, w16.y);
    *(uint2*)(vtws + rowb + ((c0 + 4) ^ swv)) = make_uint2(w16.z, w16.w);
  }
}

// ---- async stage of K tile (16 KB) + V^T tile (16 KB) for chunk-tile j into LDS buf
// LDS layout: [K0 16K | K1 16K | V0 16K | V1 16K]; each wave issues 4+4 glds16.
__device__ __forceinline__ void stage_tiles(
    unsigned char* smem, int cur,
    const unsigned short* kbase, const unsigned short* vbase,
    int j, int w, int lane)
{
  unsigned char* kdst = smem + cur * 16384;
  unsigned char* vdst = smem + 32768 + cur * 16384;
  const unsigned char* ksrc = (const unsigned char*)kbase + (size_t)j * 16384;
  const unsigned char* vsrc = (const unsigned char*)vbase + (size_t)j * 128;
#pragma unroll
  for (int i = 0; i < 4; ++i) {
    const int p = w * 4 + i;
    glds16(ksrc + p * 1024 + lane * 16, kdst + p * 1024);
  }
#pragma unroll
  for (int i = 0; i < 4; ++i) {
    const int p = w * 4 + i;
    const int dv = p * 8 + (lane >> 3);
    glds16(vsrc + (size_t)dv * 2048 + (lane & 7) * 16, vdst + p * 1024);
  }
}

// ---------------- flash attention over one chunk ----------------
// grid (qt=8, n*h=64, b=4); block 256 = 4 waves; wave owns 32 q-rows.
__global__ __launch_bounds__(256) void attn_kernel(
    const unsigned short* __restrict__ qws, const unsigned short* __restrict__ kws,
    const unsigned short* __restrict__ vtws, float* __restrict__ out)
{
  __shared__ alignas(16) unsigned char smem[65536];  // K dbuf 32K | V dbuf 32K (Q overlay in prologue)

  const int qt   = 7 - (int)blockIdx.x;  // heavy blocks first
  const int nh   = blockIdx.y;
  const int b    = blockIdx.z;
  const int t    = threadIdx.x;
  const int lane = t & 63;
  const int w    = t >> 6;
  const int c    = lane & 31;   // q index for S^T/O^T frags
  const int g    = lane >> 5;

  const size_t bnh = (size_t)b * 64 + nh;
  const unsigned short* qbase = qws + bnh * (1024 * 128) + (size_t)qt * (128 * 128);
  const unsigned short* kbase = kws + bnh * (1024 * 128);
  const unsigned short* vbase = vtws + bnh * (128 * 1024);
  const int jmax = 2 * qt + 2;

  // ---- prologue: stage Q tile (pitch 272, fits in 64K) and pull B-frags
#pragma unroll
  for (int it = 0; it < 8; ++it) {
    int u = it * 256 + t;
    int row = u >> 4, col = u & 15;
    uint4 val = ((const uint4*)qbase)[u];
    *(uint4*)(smem + row * 272 + col * 16) = val;
  }
  __syncthreads();
  const int qsub = w * 32;
  bf16x8 qf[8];  // B-frag f: q = qsub+c, dh = 16f + 8g + j
  {
    const unsigned char* qp = smem + (qsub + c) * 272 + g * 16;
#pragma unroll
    for (int f = 0; f < 8; ++f) qf[f] = *(const bf16x8*)(qp + f * 32);
  }
  __syncthreads();

  // ---- stage tile 0 (overwrites Q staging region; all waves past barrier)
  stage_tiles(smem, 0, kbase, vbase, 0, w, lane);
  asm volatile("s_waitcnt vmcnt(0)" ::: "memory");
  __syncthreads();

  f32x16 acc[4] = {};            // O^T: acc[d] = dv [32d,32d+32) x q; col=c=q
  float m_run = -INFINITY, l_run = 0.0f;
  const int q0w  = qt * 128 + qsub;
  const int rowq = q0w + c;      // this lane's q row (chunk-local)
  const int ksw  = (c & 15) << 4;  // byte-domain un-swizzle for K reads (row&15 == c&15)
  const int vsw  = (c & 15) << 3;  // byte-domain un-swizzle for V reads (dv&15 == c&15)

  int cur = 0;
  for (int j = 0; j < jmax; ++j) {
    // ---- issue next tile's direct-to-LDS loads; they fly under this tile's compute
    if (j + 1 < jmax) stage_tiles(smem, cur ^ 1, kbase, vbase, j + 1, w, lane);

    const int kv0 = j * 64;
    if (kv0 <= q0w + 31) {  // not fully masked for this wave
      const unsigned char* ktc = smem + cur * 16384;
      const unsigned char* vtc = smem + 32768 + cur * 16384;
      // ---- S^T = K . Q^T : two 32(kv) x 32(q) tiles
      f32x16 s[2];
      __builtin_amdgcn_s_setprio(1);
#pragma unroll
      for (int ks = 0; ks < 2; ++ks) {
        f32x16 a = {};
        const unsigned char* kp = ktc + (ks * 32 + c) * 256;
#pragma unroll
        for (int f = 0; f < 8; ++f) {
          bf16x8 kf = *(const bf16x8*)(kp + ((g * 16 + f * 32) ^ ksw));  // A: kv=ks*32+c, dh=16f+8g+i
          a = __builtin_amdgcn_mfma_f32_32x32x16_bf16(kf, qf[f], a, 0, 0, 0);
        }
        s[ks] = a;
      }
      __builtin_amdgcn_s_setprio(0);
      // ---- online softmax (exp2 domain; scale*log2e folded into Q)
      const bool needmask = (kv0 + 63) > q0w;
      float m0 = -3.0e38f, m1 = m0, m2 = m0, m3 = m0;  // 4-way tree max
      if (needmask) {
#pragma unroll
        for (int ks = 0; ks < 2; ++ks)
#pragma unroll
          for (int r = 0; r < 16; r += 4) {
            const int base = kv0 + ks * 32 + 8 * (r >> 2) + 4 * g;
            float v0 = (base + 0 > rowq) ? -3.0e38f : s[ks][r + 0];
            float v1 = (base + 1 > rowq) ? -3.0e38f : s[ks][r + 1];
            float v2 = (base + 2 > rowq) ? -3.0e38f : s[ks][r + 2];
            float v3 = (base + 3 > rowq) ? -3.0e38f : s[ks][r + 3];
            s[ks][r + 0] = v0; s[ks][r + 1] = v1; s[ks][r + 2] = v2; s[ks][r + 3] = v3;
            m0 = fmaxf(m0, v0); m1 = fmaxf(m1, v1); m2 = fmaxf(m2, v2); m3 = fmaxf(m3, v3);
          }
      } else {
#pragma unroll
        for (int ks = 0; ks < 2; ++ks)
#pragma unroll
          for (int r = 0; r < 16; r += 4) {
            m0 = fmaxf(m0, s[ks][r + 0]); m1 = fmaxf(m1, s[ks][r + 1]);
            m2 = fmaxf(m2, s[ks][r + 2]); m3 = fmaxf(m3, s[ks][r + 3]);
          }
      }
      float mloc = fmaxf(fmaxf(m0, m1), fmaxf(m2, m3));
      mloc = fmaxf(mloc, __shfl_xor(mloc, 32));  // both g-halves hold q=c
      if (__any(mloc > m_run)) {   // skip rescale when running max unchanged (alpha==1)
        const float mnew  = fmaxf(m_run, mloc);
        const float alpha = __builtin_amdgcn_exp2f(m_run - mnew);
        l_run *= alpha;
#pragma unroll
        for (int d = 0; d < 4; ++d)
#pragma unroll
          for (int r = 0; r < 16; ++r) acc[d][r] *= alpha;
        m_run = mnew;
      }
      float r0 = 0.0f, r1 = 0.0f, r2 = 0.0f, r3 = 0.0f;
#pragma unroll
      for (int ks = 0; ks < 2; ++ks)
#pragma unroll
        for (int r = 0; r < 16; r += 4) {
          float p0 = __builtin_amdgcn_exp2f(s[ks][r + 0] - m_run); s[ks][r + 0] = p0; r0 += p0;
          float p1 = __builtin_amdgcn_exp2f(s[ks][r + 1] - m_run); s[ks][r + 1] = p1; r1 += p1;
          float p2 = __builtin_amdgcn_exp2f(s[ks][r + 2] - m_run); s[ks][r + 2] = p2; r2 += p2;
          float p3 = __builtin_amdgcn_exp2f(s[ks][r + 3] - m_run); s[ks][r + 3] = p3; r3 += p3;
        }
      float rsum = (r0 + r1) + (r2 + r3);
      rsum += __shfl_xor(rsum, 32);
      l_run += rsum;
      // ---- pack P^T frags: S^T D-regs 4o..4o+3 ARE the 32x32x8 B-frag (k=4g+i)
      bf16x4 pfr[8];
#pragma unroll
      for (int o = 0; o < 8; ++o) {
        const int ks = o >> 2, rb = 4 * (o & 3);
        union { unsigned uu[2]; bf16x4 bv; } pk;
        pk.uu[0] = pk2(s[ks][rb + 0], s[ks][rb + 1]);
        pk.uu[1] = pk2(s[ks][rb + 2], s[ks][rb + 3]);
        pfr[o] = pk.bv;
      }
      // ---- O^T += V^T . P^T   (A: dv=32d+c, kv=8o+4g+i from LDS b64)
      __builtin_amdgcn_s_setprio(1);
#pragma unroll
      for (int d = 0; d < 4; ++d) {
        f32x16 a = acc[d];
        const unsigned char* vpd = vtc + (32 * d + c) * 128;
#pragma unroll
        for (int o = 0; o < 8; ++o) {
          bf16x4 vf = *(const bf16x4*)(vpd + ((g * 8 + o * 16) ^ vsw));
          a = __builtin_amdgcn_mfma_f32_32x32x8bf16_1k(vf, pfr[o], a, 0, 0, 0);
        }
        acc[d] = a;
      }
      __builtin_amdgcn_s_setprio(0);
    }
    // ---- drain next-tile loads (they had the whole compute phase to land), publish
    asm volatile("s_waitcnt vmcnt(0)" ::: "memory");
    __syncthreads();
    cur ^= 1;
  }

  // ---- epilogue: O = O^T/l ; lane holds q=rowq, dv = 32d + 8e + 4g + rr
  const float invl = 1.0f / l_run;
  const int n = nh >> 4, h = nh & 15;
  const size_t orow = (((size_t)b * 4096 + n * 1024 + rowq) * 16 + h) * 128;
#pragma unroll
  for (int d = 0; d < 4; ++d)
#pragma unroll
    for (int e = 0; e < 4; ++e) {
      f32x4 vv;
#pragma unroll
      for (int rr = 0; rr < 4; ++rr) vv[rr] = acc[d][4 * e + rr] * invl;
      *(f32x4*)(out + orow + 32 * d + 8 * e + 4 * g) = vv;
    }
}

extern "C" void kernel_launch(void* const* d_in, const int* in_sizes, int n_in,
                              void* d_out, int out_size, void* d_ws, size_t ws_size,
                              hipStream_t stream) {
  const float* q = (const float*)d_in[0];
  const float* k = (const float*)d_in[1];
  const float* v = (const float*)d_in[2];
  float* out = (float*)d_out;
  // ws: qws | kws | vtws, each 4*4096*16*128 bf16 = 64 MB (192 MB total)
  unsigned short* qws  = (unsigned short*)d_ws;
  unsigned short* kws  = qws + (size_t)33554432;
  unsigned short* vtws = kws + (size_t)33554432;

  // sincos table (2 MB) overlays the vtws region: consumed by rope_kernel,
  // then fully overwritten by vtrans_kernel before attn reads vtws.
  float* tab = (float*)vtws;
  rope_tab_kernel<<<1024, 256, 0, stream>>>(tab);
  rope_kernel<<<16384, 256, 0, stream>>>(q, k, tab, qws, kws);
  vtrans_kernel<<<4096, 256, 0, stream>>>(v, vtws);
  attn_kernel<<<dim3(8, 64, 4), 256, 0, stream>>>(qws, kws, vtws, out);
}